// Round 14
// baseline (2024.403 us; speedup 1.0000x reference)
//
#include <hip/hip_runtime.h>
#include <math.h>

// TreeLSTM on MI355X — round 13 kernel (resubmit after broker timeout):
// phase-merged MFMA level kernel.
// Round-12 evidence: MfmaUtil 9.6%, 36 barrier-steps/block with 4-12 MFMAs
// each, A-tiles staged 4x, 1.6e7 LDS bank conflicts (64B row stride).
// Changes: (1) merged f+iou B-tiles -> 18 steps, 16 MFMA/step/wave, h staged
// once per child; (2) LDS row pad 32->40 elems (conflict-free groups);
// (3) encoder blocks widened to 256 cols. Numerics identical to round 12.

typedef __attribute__((ext_vector_type(8))) short bf16x8;
typedef __attribute__((ext_vector_type(4))) float f32x4;

#define LDP 40   // padded LDS row length (bf16 elems); 80B stride -> 5 mod 8 line groups

__device__ __forceinline__ float sigm(float x)  { return 1.0f / (1.0f + __expf(-x)); }
__device__ __forceinline__ float tanhx(float x) { return 1.0f - 2.0f / (__expf(2.0f * x) + 1.0f); }

__device__ __forceinline__ float b2f(unsigned short u) {
    union { unsigned int i; float f; } v; v.i = ((unsigned int)u) << 16; return v.f;
}
__device__ __forceinline__ unsigned short f2b(float f) {
    union { float f; unsigned int i; } v; v.f = f;
    unsigned int r = v.i + 0x7FFFu + ((v.i >> 16) & 1u);   // round-nearest-even
    return (unsigned short)(r >> 16);
}

// ---- LDS staging: thread t -> row t>>2, 8-elem chunk (t&3)*8 (16B ops) ----

__device__ __forceinline__ void stage_a_bf16(unsigned short* dst,
        const unsigned short* src, int srcStride, int validRows, int tid) {
    const int row = tid >> 2, ch = (tid & 3) << 3;
    bf16x8 v = {0, 0, 0, 0, 0, 0, 0, 0};
    if (row < validRows)
        v = *(const bf16x8*)&src[(size_t)row * srcStride + ch];
    *(bf16x8*)&dst[row * LDP + ch] = v;
}

__device__ __forceinline__ void stage_a_fp32(unsigned short* dst,
        const float* src, int srcStride, int validRows, int tid) {
    const int row = tid >> 2, ch = (tid & 3) << 3;
    bf16x8 v = {0, 0, 0, 0, 0, 0, 0, 0};
    if (row < validRows) {
        const float4 a = *(const float4*)&src[(size_t)row * srcStride + ch];
        const float4 b = *(const float4*)&src[(size_t)row * srcStride + ch + 4];
        v[0] = (short)f2b(a.x); v[1] = (short)f2b(a.y);
        v[2] = (short)f2b(a.z); v[3] = (short)f2b(a.w);
        v[4] = (short)f2b(b.x); v[5] = (short)f2b(b.y);
        v[6] = (short)f2b(b.z); v[7] = (short)f2b(b.w);
    }
    *(bf16x8*)&dst[row * LDP + ch] = v;
}

// Merged B stage: rows 0-63 = Wf (n0..n0+63), rows 64-255 = Wiou groups g*256+n0..
__device__ __forceinline__ void stage_b_fiou(unsigned short* dst,
        const unsigned short* Wf, const unsigned short* Wiou,
        int n0, int K, int k0, int tid) {
    const int row = tid >> 2, ch = (tid & 3) << 3;
    *(bf16x8*)&dst[row * LDP + ch] =
        *(const bf16x8*)&Wf[(size_t)(n0 + row) * K + k0 + ch];
#pragma unroll
    for (int g = 0; g < 3; ++g)
        *(bf16x8*)&dst[(64 + g * 64 + row) * LDP + ch] =
            *(const bf16x8*)&Wiou[(size_t)(g * 256 + n0 + row) * K + k0 + ch];
}

// B stage for mgemm: NSUB*64 rows of Wt starting at n0
__device__ __forceinline__ void stage_b_sub(unsigned short* dst,
        const unsigned short* Wt, int n0, int K, int k0, int nsub, int tid) {
    const int row = tid >> 2, ch = (tid & 3) << 3;
    for (int s = 0; s < nsub; ++s)
        *(bf16x8*)&dst[(s * 64 + row) * LDP + ch] =
            *(const bf16x8*)&Wt[(size_t)(n0 + s * 64 + row) * K + k0 + ch];
}

__device__ __forceinline__ bf16x8 frag(const unsigned short* lds, int rowBase, int lane) {
    return *(const bf16x8*)&lds[(rowBase + (lane & 15)) * LDP + ((lane >> 4) << 3)];
}

// ---- prep: fp32 W[K][N] -> bf16 Wt[N][K] ---------------------------------
__global__ __launch_bounds__(256) void tpose_bf16(const float* __restrict__ W,
        unsigned short* __restrict__ Wt, int K, int N) {
    const int idx = blockIdx.x * 256 + threadIdx.x;
    if (idx < K * N) {
        const int nn = idx / K, kk = idx - nn * K;
        Wt[idx] = f2b(W[(size_t)kk * N + nn]);
    }
}

// ---- MFMA GEMM: Cb = relu(A @ Wt^T + bias); block = 64 rows x NSUB*64 cols
template<int NSUB, int AFP32>
__global__ __launch_bounds__(256) void mgemm(
    const void* __restrict__ Av, const unsigned short* __restrict__ Wt,
    const float* __restrict__ bias, unsigned short* __restrict__ Cb,
    int M, int N, int K)
{
    __shared__ unsigned short As[64 * LDP];
    __shared__ unsigned short Bs[NSUB * 64 * LDP];
    const int tid = threadIdx.x, lane = tid & 63, wave = tid >> 6;
    const int m0 = blockIdx.x * 64, n0 = blockIdx.y * (NSUB * 64);
    const int mr = wave * 16, fr = lane & 15, fq = lane >> 4;
    const f32x4 z = {0.f, 0.f, 0.f, 0.f};
    f32x4 acc[NSUB * 4];
#pragma unroll
    for (int j = 0; j < NSUB * 4; ++j) acc[j] = z;

    for (int k0 = 0; k0 < K; k0 += 32) {
        if (AFP32)
            stage_a_fp32(As, (const float*)Av + (size_t)m0 * K + k0, K, M - m0, tid);
        else
            stage_a_bf16(As, (const unsigned short*)Av + (size_t)m0 * K + k0, K, M - m0, tid);
        stage_b_sub(Bs, Wt, n0, K, k0, NSUB, tid);
        __syncthreads();
        const bf16x8 a = frag(As, mr, lane);
#pragma unroll
        for (int j = 0; j < NSUB * 4; ++j)
            acc[j] = __builtin_amdgcn_mfma_f32_16x16x32_bf16(a, frag(Bs, j * 16, lane), acc[j], 0, 0, 0);
        __syncthreads();
    }
#pragma unroll
    for (int j = 0; j < NSUB * 4; ++j)
#pragma unroll
        for (int i = 0; i < 4; ++i) {
            const int m = m0 + mr + fq * 4 + i;
            if (m < M) {
                const int nn = n0 + j * 16 + fr;
                Cb[(size_t)m * N + nn] = f2b(fmaxf(acc[j][i] + bias[nn], 0.f));
            }
        }
}

// ---- fused level kernel, phase-merged. LEAF=1: io path only. -------------
// Per block: 64 parents x 64 cols (n0 quadrant of 256).
//   x4 step (K=64):   A=x4p, B=[w_f | w_iou g0 g1 g2]; cm += A@w_f, io += A@w_iou
//   child t (K=256):  A=h_child, B=[u_f | u_iou]; fa = A@u_f, io += A@u_iou
//                     then cs += sigm(fa+cm+b_f)*c_child
//   epilogue: c = sigm(i)tanh(u)+cs; h = sigm(o)tanh(c)
template<int LEAF>
__global__ __launch_bounds__(256) void level_mfma(
    const unsigned short* __restrict__ x4b, int offP,
    const unsigned short* __restrict__ h_prev, const unsigned short* __restrict__ c_prev,
    const unsigned short* __restrict__ Wt_iou, const unsigned short* __restrict__ Wt_uiou,
    const float* __restrict__ b_iou,
    const unsigned short* __restrict__ Wt_f, const unsigned short* __restrict__ Wt_uf,
    const float* __restrict__ b_f,
    unsigned short* __restrict__ h_cur, unsigned short* __restrict__ c_cur,
    int P, int C)
{
    __shared__ unsigned short As[64 * LDP];
    __shared__ unsigned short Bs[256 * LDP];
    const int tid = threadIdx.x, lane = tid & 63, wave = tid >> 6;
    const int m0 = blockIdx.x * 64, n0 = blockIdx.y * 64;
    const int mr = wave * 16, fr = lane & 15, fq = lane >> 4;
    const f32x4 z = {0.f, 0.f, 0.f, 0.f};
    const int nch = (!LEAF && m0 == 0 && C > 2 * P) ? 3 : 2;  // 3rd child: j=0, odd C

    f32x4 cm[4] = {z, z, z, z};
    f32x4 cs[4] = {z, z, z, z};
    f32x4 io[3][4] = {{z, z, z, z}, {z, z, z, z}, {z, z, z, z}};

    // ---- x4 step: K=64, B = [w_f | w_iou] ----
    for (int k0 = 0; k0 < 64; k0 += 32) {
        stage_a_bf16(As, x4b + (size_t)(offP + m0) * 64 + k0, 64, P - m0, tid);
        stage_b_fiou(Bs, Wt_f, Wt_iou, n0, 64, k0, tid);
        __syncthreads();
        const bf16x8 a = frag(As, mr, lane);
        if (!LEAF) {
#pragma unroll
            for (int ns = 0; ns < 4; ++ns)
                cm[ns] = __builtin_amdgcn_mfma_f32_16x16x32_bf16(a, frag(Bs, ns * 16, lane), cm[ns], 0, 0, 0);
        }
#pragma unroll
        for (int g = 0; g < 3; ++g)
#pragma unroll
            for (int ns = 0; ns < 4; ++ns)
                io[g][ns] = __builtin_amdgcn_mfma_f32_16x16x32_bf16(a, frag(Bs, 64 + g * 64 + ns * 16, lane), io[g][ns], 0, 0, 0);
        __syncthreads();
    }

    // ---- child steps: K=256, B = [u_f | u_iou] ----
    if (!LEAF) {
        for (int t = 0; t < nch; ++t) {
            f32x4 fa[4] = {z, z, z, z};
            const int base = t * P + m0;
            for (int k0 = 0; k0 < 256; k0 += 32) {
                stage_a_bf16(As, h_prev + (size_t)base * 256 + k0, 256, C - base, tid);
                stage_b_fiou(Bs, Wt_uf, Wt_uiou, n0, 256, k0, tid);
                __syncthreads();
                const bf16x8 a = frag(As, mr, lane);
#pragma unroll
                for (int ns = 0; ns < 4; ++ns)
                    fa[ns] = __builtin_amdgcn_mfma_f32_16x16x32_bf16(a, frag(Bs, ns * 16, lane), fa[ns], 0, 0, 0);
#pragma unroll
                for (int g = 0; g < 3; ++g)
#pragma unroll
                    for (int ns = 0; ns < 4; ++ns)
                        io[g][ns] = __builtin_amdgcn_mfma_f32_16x16x32_bf16(a, frag(Bs, 64 + g * 64 + ns * 16, lane), io[g][ns], 0, 0, 0);
                __syncthreads();
            }
#pragma unroll
            for (int ns = 0; ns < 4; ++ns)
#pragma unroll
                for (int i = 0; i < 4; ++i) {
                    const int m = m0 + mr + fq * 4 + i;
                    const int crow = t * P + m;
                    if (m < P && crow < C) {
                        const int nn = n0 + ns * 16 + fr;
                        const float fv = sigm(fa[ns][i] + cm[ns][i] + b_f[nn]);
                        cs[ns][i] += fv * b2f(c_prev[(size_t)crow * 256 + nn]);
                    }
                }
        }
    }

    // ---- epilogue: LSTM cell at fragment coordinates ----
#pragma unroll
    for (int ns = 0; ns < 4; ++ns)
#pragma unroll
        for (int i = 0; i < 4; ++i) {
            const int m = m0 + mr + fq * 4 + i;
            if (m < P) {
                const int nn = n0 + ns * 16 + fr;
                const float iv = io[0][ns][i] + b_iou[nn];
                const float ov = io[1][ns][i] + b_iou[256 + nn];
                const float uv = io[2][ns][i] + b_iou[512 + nn];
                const float cv = sigm(iv) * tanhx(uv) + cs[ns][i];
                c_cur[(size_t)m * 256 + nn] = f2b(cv);
                h_cur[(size_t)m * 256 + nn] = f2b(sigm(ov) * tanhx(cv));
            }
        }
}

// ---- classifier (bf16 h) -------------------------------------------------
__global__ __launch_bounds__(256) void cls_kernel(
    const unsigned short* __restrict__ h, const float* __restrict__ cls_w,
    const float* __restrict__ cls_b, float* __restrict__ out, int P)
{
    __shared__ float hs[32][257];
    __shared__ float wsm[256 * 8];
    __shared__ float bs[8];
    const int tid = threadIdx.x;
    const int row0 = blockIdx.x * 32;
    for (int i = tid; i < 2048; i += 256) wsm[i] = cls_w[i];
    if (tid < 8) bs[tid] = cls_b[tid];
    for (int it = 0; it < 32; ++it) {
        const int row = row0 + it;
        hs[it][tid] = (row < P) ? b2f(h[(size_t)row * 256 + tid]) : 0.f;
    }
    __syncthreads();
    const int r = tid >> 3, j = tid & 7;
    float acc = bs[j];
#pragma unroll 4
    for (int k = 0; k < 256; ++k) acc += hs[r][k] * wsm[k * 8 + j];
    float mx = acc;
    for (int off = 1; off < 8; off <<= 1) mx = fmaxf(mx, __shfl_xor(mx, off, 8));
    const float e = __expf(acc - mx);
    float s = e;
    for (int off = 1; off < 8; off <<= 1) s += __shfl_xor(s, off, 8);
    const int row = row0 + r;
    if (row < P) out[(size_t)row * 8 + j] = e / s;
}

// ---------------------------------------------------------------------------
extern "C" void kernel_launch(void* const* d_in, const int* in_sizes, int n_in,
                              void* d_out, int out_size, void* d_ws, size_t ws_size,
                              hipStream_t stream)
{
    (void)n_in; (void)out_size; (void)ws_size;
    const float* features = (const float*)d_in[0];
    const float* enc_w1 = (const float*)d_in[5];
    const float* enc_b1 = (const float*)d_in[6];
    const float* enc_w2 = (const float*)d_in[7];
    const float* enc_b2 = (const float*)d_in[8];
    const float* enc_w3 = (const float*)d_in[9];
    const float* enc_b3 = (const float*)d_in[10];
    const float* enc_w4 = (const float*)d_in[11];
    const float* enc_b4 = (const float*)d_in[12];
    const float* w_iou  = (const float*)d_in[13];
    const float* b_iou  = (const float*)d_in[14];
    const float* u_iou  = (const float*)d_in[15];
    const float* w_f    = (const float*)d_in[16];
    const float* b_f    = (const float*)d_in[17];
    const float* u_f    = (const float*)d_in[18];
    const float* cls_w  = (const float*)d_in[19];
    const float* cls_b  = (const float*)d_in[20];
    float* out = (float*)d_out;

    const int n = in_sizes[0] / 64;

    int sz[32], nl = 0;
    for (int s = 100000; s >= 1; s /= 2) sz[nl++] = s;
    int off[33];
    off[0] = 0;
    for (int i = 0; i < nl; ++i) off[i + 1] = off[i] + sz[i];

    // Workspace (bf16 shorts), total ~180.3 MB (< proven 204.8 MB budget):
    unsigned short* wsb = (unsigned short*)d_ws;
    unsigned short* Wt_e1   = wsb;                      // [512][64]   32768
    unsigned short* Wt_e2   = Wt_e1 + 32768;            // [256][512]  131072
    unsigned short* Wt_e3   = Wt_e2 + 131072;           // [128][256]  32768
    unsigned short* Wt_e4   = Wt_e3 + 32768;            // [64][128]   8192
    unsigned short* Wt_iou  = Wt_e4 + 8192;             // [768][64]   49152
    unsigned short* Wt_uiou = Wt_iou + 49152;           // [768][256]  196608
    unsigned short* Wt_f    = Wt_uiou + 196608;         // [256][64]   16384
    unsigned short* Wt_uf   = Wt_f + 16384;             // [256][256]  65536
    unsigned short* x4b     = Wt_uf + 65536;            // n*64
    unsigned short* hA      = x4b + (size_t)n * 64;     // 100000*256
    unsigned short* hB      = hA + (size_t)100000 * 256;
    unsigned short* cA      = hB + (size_t)50000 * 256;
    unsigned short* cB      = cA + (size_t)100000 * 256;
    unsigned short* hbuf[2] = {hA, hB};
    unsigned short* cbuf[2] = {cA, cB};

    // ---- prep: weights -> bf16, transposed [N][K] ----
    tpose_bf16<<<(64 * 512 + 255) / 256, 256, 0, stream>>>(enc_w1, Wt_e1, 64, 512);
    tpose_bf16<<<(512 * 256 + 255) / 256, 256, 0, stream>>>(enc_w2, Wt_e2, 512, 256);
    tpose_bf16<<<(256 * 128 + 255) / 256, 256, 0, stream>>>(enc_w3, Wt_e3, 256, 128);
    tpose_bf16<<<(128 * 64 + 255) / 256, 256, 0, stream>>>(enc_w4, Wt_e4, 128, 64);
    tpose_bf16<<<(64 * 768 + 255) / 256, 256, 0, stream>>>(w_iou, Wt_iou, 64, 768);
    tpose_bf16<<<(256 * 768 + 255) / 256, 256, 0, stream>>>(u_iou, Wt_uiou, 256, 768);
    tpose_bf16<<<(64 * 256 + 255) / 256, 256, 0, stream>>>(w_f, Wt_f, 64, 256);
    tpose_bf16<<<(256 * 256 + 255) / 256, 256, 0, stream>>>(u_f, Wt_uf, 256, 256);

    // ---- Encoder MLP, 4 chunks of <=50000; bf16 temps alias h/c pool ----
    const int CR = 50000;
    unsigned short* t1b = hA;   // 50000*512 = 25.6M shorts (== hA)
    unsigned short* t2b = hB;   // 50000*256 = 12.8M (== hB)
    unsigned short* t3b = cA;   // 50000*128 =  6.4M (cA head)
    for (int ch = 0; ch * CR < n; ++ch) {
        const int r0 = ch * CR;
        const int M = (n - r0 < CR) ? (n - r0) : CR;
        mgemm<4, 1><<<dim3((M + 63) / 64, 2), 256, 0, stream>>>(
            features + (size_t)r0 * 64, Wt_e1, enc_b1, t1b, M, 512, 64);
        mgemm<4, 0><<<dim3((M + 63) / 64, 1), 256, 0, stream>>>(
            t1b, Wt_e2, enc_b2, t2b, M, 256, 512);
        mgemm<2, 0><<<dim3((M + 63) / 64, 1), 256, 0, stream>>>(
            t2b, Wt_e3, enc_b3, t3b, M, 128, 256);
        mgemm<1, 0><<<dim3((M + 63) / 64, 1), 256, 0, stream>>>(
            t3b, Wt_e4, enc_b4, x4b + (size_t)r0 * 64, M, 64, 128);
    }

    // ---- Level 0 (leaves) + classifier ----
    {
        const int P = sz[0];
        level_mfma<1><<<dim3((P + 63) / 64, 4), 256, 0, stream>>>(
            x4b, 0, (const unsigned short*)nullptr, (const unsigned short*)nullptr,
            Wt_iou, Wt_uiou, b_iou, Wt_f, Wt_uf, b_f, hA, cA, P, 0);
        cls_kernel<<<dim3((P + 31) / 32), 256, 0, stream>>>(hA, cls_w, cls_b, out, P);
    }

    // ---- Levels 1..nl-1 ----
    for (int l = 1; l < nl; ++l) {
        const int P = sz[l], C = sz[l - 1];
        unsigned short* hp = hbuf[(l - 1) & 1]; unsigned short* cp = cbuf[(l - 1) & 1];
        unsigned short* hc = hbuf[l & 1];       unsigned short* cc = cbuf[l & 1];
        level_mfma<0><<<dim3((P + 63) / 64, 4), 256, 0, stream>>>(
            x4b, off[l], hp, cp, Wt_iou, Wt_uiou, b_iou, Wt_f, Wt_uf, b_f,
            hc, cc, P, C);
        cls_kernel<<<dim3((P + 31) / 32), 256, 0, stream>>>(
            hc, cls_w, cls_b, out + (size_t)off[l] * 8, P);
    }
}